// Round 4
// baseline (1986.906 us; speedup 1.0000x reference)
//
#include <hip/hip_runtime.h>
#include <hip/hip_bf16.h>

// ---------------- problem constants ----------------
#define NA 10
#define NB 1024
#define NY 94
#define NR 256
#define NH 128
#define NT 50
#define FSC 0.1f
#define NIN 350
#define K1 352            // padded enc K: [h(256) | y(94) | pad(2)]
#define ENC_S 376         // enc LDS row stride (bf16): 16B-aligned rows
#define D_S 136           // d1/d2 LDS row stride (bf16)
#define BT 64             // batch rows per block
#define LOG2PI 1.8378770664093453f

typedef __attribute__((ext_vector_type(8))) short frag_b16;
typedef __attribute__((ext_vector_type(4))) float frag_f32;

__device__ __forceinline__ frag_f32 mfma16(frag_b16 a, frag_b16 b, frag_f32 c) {
    return __builtin_amdgcn_mfma_f32_16x16x32_bf16(a, b, c, 0, 0, 0);
}
__device__ __forceinline__ unsigned short f2bf(float f) {
    unsigned int u = __float_as_uint(f);
    u = (u + 0x7fffu + ((u >> 16) & 1u)) >> 16;
    return (unsigned short)u;
}
__device__ __forceinline__ float bf2f(unsigned short h) {
    return __uint_as_float(((unsigned int)h) << 16);
}
__device__ __forceinline__ float sigm(float x) { return 1.f / (1.f + __expf(-x)); }
__device__ __forceinline__ float tanh_c(float x) {
    float xx = fminf(fmaxf(x, -15.f), 15.f);
    float e = __expf(2.f * xx);
    return (e - 1.f) / (e + 1.f);
}
__device__ __forceinline__ float softp(float x) {
    return fmaxf(x, 0.f) + log1pf(__expf(-fabsf(x)));
}

// ---------------- prep kernels (unchanged from R3) ----------------
__global__ void k_prep_wrz(const float* __restrict__ w_ih, const float* __restrict__ w_hh,
                           unsigned short* __restrict__ dst) {
    int i = blockIdx.x * 256 + threadIdx.x;
    if (i >= NA * 512 * K1) return;
    int k = i % K1;
    int g = (i / K1) % 512;
    int a = i / (K1 * 512);
    float v = 0.f;
    if (k < 256)      v = w_ih[(size_t)(a * 768 + g) * NIN + NY + k] + w_hh[(size_t)(a * 768 + g) * NR + k];
    else if (k < 350) v = w_ih[(size_t)(a * 768 + g) * NIN + (k - 256)];
    dst[i] = f2bf(v);
}
__global__ void k_prep_wni(const float* __restrict__ w_ih, unsigned short* __restrict__ dst) {
    int i = blockIdx.x * 256 + threadIdx.x;
    if (i >= NA * 256 * K1) return;
    int k = i % K1;
    int g = (i / K1) % 256;
    int a = i / (K1 * 256);
    float v = 0.f;
    if (k < 256)      v = w_ih[(size_t)(a * 768 + 512 + g) * NIN + NY + k];
    else if (k < 350) v = w_ih[(size_t)(a * 768 + 512 + g) * NIN + (k - 256)];
    dst[i] = f2bf(v);
}
__global__ void k_prep_wnh(const float* __restrict__ w_hh, unsigned short* __restrict__ dst) {
    int i = blockIdx.x * 256 + threadIdx.x;
    if (i >= NA * 256 * NR) return;
    int k = i % NR;
    int g = (i / NR) % 256;
    int a = i / (NR * 256);
    dst[i] = f2bf(w_hh[(size_t)(a * 768 + 512 + g) * NR + k]);
}
__global__ void k_convert(const float* __restrict__ src, unsigned short* __restrict__ dst, int n) {
    int i = blockIdx.x * 256 + threadIdx.x;
    if (i < n) dst[i] = f2bf(src[i]);
}

// ---------------- main persistent kernel ----------------
// 1024 threads = 16 waves (4/SIMD, 1 block/CU via LDS). Wave w: GRU cols [w*16, w*16+16).
__launch_bounds__(1024, 4)
__global__ void k_main(const float* __restrict__ states,
                       const unsigned short* __restrict__ Wrz,  // [A][512][352]
                       const unsigned short* __restrict__ Wni,  // [A][256][352]
                       const unsigned short* __restrict__ Wnh,  // [A][256][256]
                       const unsigned short* __restrict__ D1w,  // [A][128][256]
                       const unsigned short* __restrict__ D2w,  // [A][128][128]
                       const float* __restrict__ b_ih, const float* __restrict__ b_hh,
                       const float* __restrict__ d1_b, const float* __restrict__ d2_b,
                       const float* __restrict__ m_w,  const float* __restrict__ m_b,
                       const float* __restrict__ s_w,  const float* __restrict__ s_b,
                       int* __restrict__ ctrl,
                       float* __restrict__ out)
{
    __shared__ unsigned short enc[2][BT * ENC_S];
    __shared__ unsigned short d1buf[BT * D_S];
    __shared__ unsigned short d2buf[BT * D_S];
    __shared__ float wls[4 * NH];
    __shared__ int s_p;

    const int tid = threadIdx.x;

    // XCD-measured work claim (kept from R3; harmless)
    if (tid == 0) {
        unsigned int xcc = __builtin_amdgcn_s_getreg(63508) & 7u; // HW_REG_XCC_ID
        int slot = atomicAdd(&ctrl[xcc], 1);
        int p = -1;
        if (slot < 20) {
            int cand = (int)xcc * 20 + slot;
            if (atomicCAS(&ctrl[16 + cand], 0, 1) == 0) p = cand;
        }
        for (int i = 0; p < 0 && i < 160; ++i) {
            int cand = ((int)xcc * 20 + i) % 160;
            if (atomicCAS(&ctrl[16 + cand], 0, 1) == 0) p = cand;
        }
        s_p = p;
    }
    for (int i = tid; i < BT * ENC_S; i += 1024) { enc[0][i] = 0; enc[1][i] = 0; }
    __syncthreads();

    const int p  = s_p;
    const int a  = p >> 4;
    const int b0 = (p & 15) * BT;

    const int w    = tid >> 6;
    const int lane = tid & 63;
    const int quad = lane >> 4;
    const int l16  = lane & 15;
    const int c0   = w * 16;
    const int koff = quad * 8;

    const unsigned short* Wrza = Wrz + (size_t)a * 512 * K1;
    const unsigned short* Wnia = Wni + (size_t)a * 256 * K1;
    const unsigned short* Wnha = Wnh + (size_t)a * 256 * NR;
    const unsigned short* D1a  = D1w + (size_t)a * NH * NR;
    const unsigned short* D2a  = D2w + (size_t)a * NH * NH;

    // t-invariant per-wave weight row bases
    const unsigned short* rowR  = Wrza + (size_t)(      c0 + l16) * K1;
    const unsigned short* rowZ  = Wrza + (size_t)(256 + c0 + l16) * K1;
    const unsigned short* rowI  = Wnia + (size_t)(c0 + l16) * K1;
    const unsigned short* rowH  = Wnha + (size_t)(c0 + l16) * NR;
    const unsigned short* rowD1 = D1a  + (size_t)(c0 + l16) * NR;

    if (tid < 512) {
        int o = tid >> 7, k = tid & 127;
        wls[tid] = (o < 2) ? m_w[(size_t)(a * 2 + o) * NH + k]
                           : s_w[(size_t)(a * 2 + (o - 2)) * NH + k];
    }
    // stage y_0 into enc[0] (nontemporal: states streams once)
    {
        const int row = tid >> 4, c16 = tid & 15;
        const float* yp = states + (((size_t)0 * NA + a) * NB + (b0 + row)) * NY;
        #pragma unroll
        for (int j = 0; j < 6; ++j) {
            int c = c16 * 6 + j;
            if (c < NY) enc[0][row * ENC_S + 256 + c] = f2bf(__builtin_nontemporal_load(yp + c));
        }
    }
    float accL = 0.f, accEp = 0.f, accEv = 0.f;
    __syncthreads();

    const frag_f32 z4 = {0.f, 0.f, 0.f, 0.f};

    for (int t = 0; t < NT; ++t) {
        unsigned short* cur = enc[t & 1];
        unsigned short* nxt = enc[(t + 1) & 1];

        // ============ pass A: rz GEMM (K=352) + d1 GEMM (K=256, waves 0-7) ============
        // depth-3 prefetch: 4-slot circular for bR/bZ, 3-slot depth-2 for bD1
        frag_f32 Cr[4], Cz[4], Cd1[4];
        #pragma unroll
        for (int mt = 0; mt < 4; ++mt) { Cr[mt] = z4; Cz[mt] = z4; Cd1[mt] = z4; }
        frag_b16 bR[4], bZ[4], bD1[3];
        #pragma unroll
        for (int i = 0; i < 3; ++i) {
            bR[i] = *(const frag_b16*)&rowR[i * 32 + koff];
            bZ[i] = *(const frag_b16*)&rowZ[i * 32 + koff];
        }
        if (w < 8) {
            bD1[0] = *(const frag_b16*)&rowD1[koff];
            bD1[1] = *(const frag_b16*)&rowD1[32 + koff];
        }
        #pragma unroll
        for (int ks = 0; ks < 11; ++ks) {
            if (ks + 3 < 11) {
                const int kk = (ks + 3) * 32 + koff;
                bR[(ks + 3) & 3] = *(const frag_b16*)&rowR[kk];
                bZ[(ks + 3) & 3] = *(const frag_b16*)&rowZ[kk];
            }
            if (w < 8 && ks + 2 < 8)
                bD1[(ks + 2) % 3] = *(const frag_b16*)&rowD1[(ks + 2) * 32 + koff];
            const int kk = ks * 32 + koff;
            frag_b16 am[4];
            #pragma unroll
            for (int mt = 0; mt < 4; ++mt)
                am[mt] = *(const frag_b16*)&cur[(mt * 16 + l16) * ENC_S + kk];
            #pragma unroll
            for (int mt = 0; mt < 4; ++mt) {
                Cr[mt] = mfma16(am[mt], bR[ks & 3], Cr[mt]);
                Cz[mt] = mfma16(am[mt], bZ[ks & 3], Cz[mt]);
            }
            if (w < 8 && ks < 8) {
                #pragma unroll
                for (int mt = 0; mt < 4; ++mt) Cd1[mt] = mfma16(am[mt], bD1[ks % 3], Cd1[mt]);
            }
        }
        // ---- epilogue A ----
        if (w < 8) {
            const float db = d1_b[a * NH + c0 + l16];
            #pragma unroll
            for (int mt = 0; mt < 4; ++mt)
                #pragma unroll
                for (int rg = 0; rg < 4; ++rg) {
                    const int row = mt * 16 + quad * 4 + rg;
                    float v = Cd1[mt][rg] + db;
                    d1buf[row * D_S + c0 + l16] = f2bf(v > 0.f ? v : 0.f);
                }
        }
        {
            const int col = c0 + l16;
            const float brz = b_ih[a * 768 + col]       + b_hh[a * 768 + col];
            const float bzz = b_ih[a * 768 + 256 + col] + b_hh[a * 768 + 256 + col];
            #pragma unroll
            for (int mt = 0; mt < 4; ++mt)
                #pragma unroll
                for (int rg = 0; rg < 4; ++rg) {
                    Cr[mt][rg] = sigm(Cr[mt][rg] + brz);
                    Cz[mt][rg] = sigm(Cz[mt][rg] + bzz);
                }
        }

        // ============ pass B: i_n (K=352) + h_n (K=256) ============
        // y_{t+1} prefetched into regs at pass start (nontemporal, hides under GEMM)
        float yreg[6];
        {
            const int row = tid >> 4, c16 = tid & 15;
            const float* yp = states + (((size_t)(t + 1) * NA + a) * NB + (b0 + row)) * NY;
            #pragma unroll
            for (int j = 0; j < 6; ++j) {
                int c = c16 * 6 + j;
                yreg[j] = (c < NY) ? __builtin_nontemporal_load(yp + c) : 0.f;
            }
        }
        frag_f32 Ci[4], Ch[4];
        #pragma unroll
        for (int mt = 0; mt < 4; ++mt) { Ci[mt] = z4; Ch[mt] = z4; }
        frag_b16 bI[4], bH[4];
        #pragma unroll
        for (int i = 0; i < 3; ++i) {
            bI[i] = *(const frag_b16*)&rowI[i * 32 + koff];
            bH[i] = *(const frag_b16*)&rowH[i * 32 + koff];
        }
        #pragma unroll
        for (int ks = 0; ks < 11; ++ks) {
            if (ks + 3 < 11)
                bI[(ks + 3) & 3] = *(const frag_b16*)&rowI[(ks + 3) * 32 + koff];
            if (ks + 3 < 8)
                bH[(ks + 3) & 3] = *(const frag_b16*)&rowH[(ks + 3) * 32 + koff];
            const int kk = ks * 32 + koff;
            frag_b16 am[4];
            #pragma unroll
            for (int mt = 0; mt < 4; ++mt)
                am[mt] = *(const frag_b16*)&cur[(mt * 16 + l16) * ENC_S + kk];
            #pragma unroll
            for (int mt = 0; mt < 4; ++mt) {
                Ci[mt] = mfma16(am[mt], bI[ks & 3], Ci[mt]);
                if (ks < 8) Ch[mt] = mfma16(am[mt], bH[ks & 3], Ch[mt]);
            }
        }
        // ---- epilogue B: gates, h update, y store ----
        {
            const int col = c0 + l16;
            const float bin = b_ih[a * 768 + 512 + col];
            const float bhn = b_hh[a * 768 + 512 + col];
            #pragma unroll
            for (int mt = 0; mt < 4; ++mt)
                #pragma unroll
                for (int rg = 0; rg < 4; ++rg) {
                    const int row = mt * 16 + quad * 4 + rg;
                    const float r = Cr[mt][rg];
                    const float z = Cz[mt][rg];
                    const float n = tanh_c(Ci[mt][rg] + bin + r * (Ch[mt][rg] + bhn));
                    const float hold = bf2f(cur[row * ENC_S + col]);
                    const float hnew = (1.f - z) * n + z * hold;
                    nxt[row * ENC_S + col] = f2bf(hnew);
                }
        }
        {
            const int row = tid >> 4, c16 = tid & 15;
            #pragma unroll
            for (int j = 0; j < 6; ++j) {
                int c = c16 * 6 + j;
                if (c < NY) nxt[row * ENC_S + 256 + c] = f2bf(yreg[j]);
            }
        }
        // ---- prefetch d2 weights + loss rows (before barrier; used after) ----
        const int dcol2 = (w >> 1) * 16;
        const int m0    = (w & 1) * 2;
        frag_b16 bD2[4];
        #pragma unroll
        for (int ks = 0; ks < 4; ++ks)
            bD2[ks] = *(const frag_b16*)&D2a[(size_t)(dcol2 + l16) * NH + ks * 32 + koff];
        float lf[8];
        if (tid < 256) {
            const int row = tid >> 2;
            const float* f0 = states + (((size_t)t * NA + a) * NB + (b0 + row)) * NY + 4 * a;
            const float* f1 = states + (((size_t)(t + 1) * NA + a) * NB + (b0 + row)) * NY + 4 * a;
            #pragma unroll
            for (int j = 0; j < 4; ++j) {
                lf[j]     = __builtin_nontemporal_load(f0 + j);
                lf[4 + j] = __builtin_nontemporal_load(f1 + j);
            }
        }
        __syncthreads();   // barrier 1 of 2

        // ============ pass C: d2 GEMM (K=128), all 16 waves ============
        frag_f32 Cd2[2] = {z4, z4};
        #pragma unroll
        for (int ks = 0; ks < 4; ++ks) {
            #pragma unroll
            for (int mi = 0; mi < 2; ++mi) {
                frag_b16 am2 = *(const frag_b16*)&d1buf[((m0 + mi) * 16 + l16) * D_S + ks * 32 + koff];
                Cd2[mi] = mfma16(am2, bD2[ks], Cd2[mi]);
            }
        }
        {
            const float db = d2_b[a * NH + dcol2 + l16];
            #pragma unroll
            for (int mi = 0; mi < 2; ++mi)
                #pragma unroll
                for (int rg = 0; rg < 4; ++rg) {
                    const int row = (m0 + mi) * 16 + quad * 4 + rg;
                    float v = Cd2[mi][rg] + db;
                    d2buf[row * D_S + dcol2 + l16] = f2bf(v > 0.f ? v : 0.f);
                }
        }
        __syncthreads();   // barrier 2 of 2

        // ============ heads + loss: waves 0-3; waves 4-15 run ahead ============
        if (tid < 256) {
            const int row = tid >> 2, o = tid & 3;
            float acc = (o < 2) ? m_b[a * 2 + o] : s_b[a * 2 + (o - 2)];
            const unsigned short* dp = &d2buf[row * D_S];
            const float* wp = &wls[o * NH];
            #pragma unroll
            for (int kb = 0; kb < 16; ++kb) {
                frag_b16 dv = *(const frag_b16*)&dp[kb * 8];
                float4 w0 = *(const float4*)&wp[kb * 8];
                float4 w1 = *(const float4*)&wp[kb * 8 + 4];
                acc += bf2f((unsigned short)dv[0]) * w0.x + bf2f((unsigned short)dv[1]) * w0.y
                     + bf2f((unsigned short)dv[2]) * w0.z + bf2f((unsigned short)dv[3]) * w0.w
                     + bf2f((unsigned short)dv[4]) * w1.x + bf2f((unsigned short)dv[5]) * w1.y
                     + bf2f((unsigned short)dv[6]) * w1.z + bf2f((unsigned short)dv[7]) * w1.w;
            }
            const float v1 = __shfl_xor(acc, 1);
            const float v2 = __shfl_xor(acc, 2);
            const float v3 = __shfl_xor(acc, 3);
            if (o == 0) {
                const float mm0 = acc, mm1 = v1;
                const float s0 = softp(v2), s1 = softp(v3);
                const float x0 = lf[6], x1 = lf[7];
                const float t0 = (x0 - mm0) / s0, t1 = (x1 - mm1) / s1;
                accL += 0.5f * (t0 * t0 + t1 * t1 + 2.f * (__logf(s0) + __logf(s1)) + 2.f * LOG2PI);
                const float e0 = lf[0] + lf[2] * FSC - lf[4];
                const float e1 = lf[1] + lf[3] * FSC - lf[5];
                accEp += sqrtf(e0 * e0 + e1 * e1);
                const float g0 = mm0 - x0, g1 = mm1 - x1;
                accEv += sqrtf(g0 * g0 + g1 * g1);
            }
        }
    }

    if (tid < 256) {
        float L = accL, E = accEp, V = accEv;
        #pragma unroll
        for (int off = 32; off; off >>= 1) {
            L += __shfl_down(L, off);
            E += __shfl_down(E, off);
            V += __shfl_down(V, off);
        }
        if ((tid & 63) == 0) {
            const float inv = 1.f / (float)(NT * NA);
            atomicAdd(&out[0], L * inv);
            atomicAdd(&out[1], E * inv);
            atomicAdd(&out[2], V * inv);
        }
    }
}

extern "C" void kernel_launch(void* const* d_in, const int* in_sizes, int n_in,
                              void* d_out, int out_size, void* d_ws, size_t ws_size,
                              hipStream_t stream) {
    const float* states = (const float*)d_in[0];
    const float* w_ih   = (const float*)d_in[1];
    const float* w_hh   = (const float*)d_in[2];
    const float* b_ih   = (const float*)d_in[3];
    const float* b_hh   = (const float*)d_in[4];
    const float* d1_w   = (const float*)d_in[5];
    const float* d1_b   = (const float*)d_in[6];
    const float* d2_w   = (const float*)d_in[7];
    const float* d2_b   = (const float*)d_in[8];
    const float* m_w    = (const float*)d_in[9];
    const float* m_b    = (const float*)d_in[10];
    const float* s_w    = (const float*)d_in[11];
    const float* s_b    = (const float*)d_in[12];

    int* ctrl = (int*)d_ws;
    unsigned short* Wrz = (unsigned short*)((char*)d_ws + 1024);
    unsigned short* Wni = Wrz + (size_t)NA * 512 * K1;
    unsigned short* Wnh = Wni + (size_t)NA * 256 * K1;
    unsigned short* D1  = Wnh + (size_t)NA * 256 * NR;
    unsigned short* D2  = D1  + (size_t)NA * NH * NR;

    hipMemsetAsync(d_out, 0, 3 * sizeof(float), stream);
    hipMemsetAsync(d_ws, 0, 1024, stream);

    const int nrz = NA * 512 * K1;
    k_prep_wrz<<<(nrz + 255) / 256, 256, 0, stream>>>(w_ih, w_hh, Wrz);
    const int nni = NA * 256 * K1;
    k_prep_wni<<<(nni + 255) / 256, 256, 0, stream>>>(w_ih, Wni);
    const int nnh = NA * 256 * NR;
    k_prep_wnh<<<(nnh + 255) / 256, 256, 0, stream>>>(w_hh, Wnh);
    const int nd1 = NA * NH * NR;
    k_convert<<<(nd1 + 255) / 256, 256, 0, stream>>>(d1_w, D1, nd1);
    const int nd2 = NA * NH * NH;
    k_convert<<<(nd2 + 255) / 256, 256, 0, stream>>>(d2_w, D2, nd2);

    k_main<<<dim3(160), dim3(1024), 0, stream>>>(states, Wrz, Wni, Wnh, D1, D2,
                                                 b_ih, b_hh, d1_b, d2_b,
                                                 m_w, m_b, s_w, s_b, ctrl, (float*)d_out);
}